// Round 10
// baseline (269.310 us; speedup 1.0000x reference)
//
#include <hip/hip_runtime.h>
#include <hip/hip_bf16.h>
#include <hip/hip_cooperative_groups.h>

namespace cg = cooperative_groups;

#define N_NODES 50000
#define N_EDGES 800000
#define IN_FEATS 128
#define NUM_HEADS 4
#define OUT_FEATS 32
#define HF 128           // NUM_HEADS * OUT_FEATS
#define NEG_SLOPE 0.2f
#define NB 196           // buckets of 256 dst nodes: ceil(50000/256)
#define CHUNK 4096       // edges per bucket-binning block (196*4096 >= 800000)

typedef __attribute__((ext_vector_type(8))) short bf16x8;
typedef __attribute__((ext_vector_type(4))) float f32x4;

__device__ __forceinline__ unsigned short f2bf(float f) {
    unsigned u = __float_as_uint(f);
    unsigned r = u + 0x7FFFu + ((u >> 16) & 1u);   // RNE
    return (unsigned short)(r >> 16);
}
__device__ __forceinline__ float bf2f(unsigned short v) {
    return __uint_as_float((unsigned)v << 16);
}
// unpack 2 packed bf16 from a u32
__device__ __forceinline__ void bf2x2(unsigned u, float& lo, float& hi) {
    lo = __uint_as_float(u << 16);
    hi = __uint_as_float(u & 0xFFFF0000u);
}

// ---------------------------------------------------------------------------
// K0 (cooperative, 196 blocks x 256 thr): the whole CSR build in one kernel.
//  pre : blocks 0..15 also pack Wfc||Widn into MFMA B-fragment order (bf16)
//  ph1 : per-block LDS histogram of dst>>8 for its CHUNK -> global bhist
//  ph2 : block 0 scans bhist[196] -> bstart, bcur         (grid.sync before)
//  ph3 : reserve per-block runs (REUSING the ph1 LDS hist — no dst re-read),
//        scatter (dst16|src16) into bucket regions of ebuf (grid.sync before)
//  ph4 : block b counting-sorts bucket b -> ssrc (ushort) + row_start
// ---------------------------------------------------------------------------
__global__ __launch_bounds__(256) void build_csr(
    const float* __restrict__ Wfc,
    const float* __restrict__ Widn,
    unsigned short* __restrict__ Bp,
    const int* __restrict__ src,
    const int* __restrict__ dst,
    int* __restrict__ bhist,
    int* __restrict__ bcur,
    int* __restrict__ bstart,
    int* __restrict__ row_start,
    unsigned* __restrict__ ebuf,
    unsigned short* __restrict__ ssrc)
{
    cg::grid_group grid = cg::this_grid();
    __shared__ int lh[256];    // ph1/ph3: bucket hist (196 used); ph4: per-dst base
    __shared__ int aux[256];   // ph2: scan; ph3: lcnt; ph4: scan
    __shared__ int aux2[256];  // ph3: gbase; ph4: rank cursors
    const int b   = blockIdx.x;
    const int tid = threadIdx.x;

    // ---- pre: pack B (blocks 0..15) ----
    if (b < 16) {
        const int nt = b;
        const int ks = tid >> 6;
        const int l  = tid & 63;
        const int col = nt * 16 + (l & 15);
        const int k0  = ks * 32 + (l >> 4) * 8;
        unsigned short v[8];
        #pragma unroll
        for (int j = 0; j < 8; ++j) {
            const int k = k0 + j;
            const float x = (col < HF) ? Wfc[k * HF + col] : Widn[k * HF + (col - HF)];
            v[j] = f2bf(x);
        }
        *(uint4*)&Bp[(size_t)(((nt * 4 + ks) * 64) + l) * 8] = *(const uint4*)v;
    }

    // ---- ph1: LDS histogram of own chunk ----
    for (int i = tid; i < NB; i += 256) lh[i] = 0;
    __syncthreads();
    const int e0 = b * CHUNK;
    for (int k = tid; k < CHUNK; k += 256) {
        const int e = e0 + k;
        if (e < N_EDGES) atomicAdd(&lh[dst[e] >> 8], 1);
    }
    __syncthreads();
    for (int i = tid; i < NB; i += 256)
        if (lh[i]) atomicAdd(&bhist[i], lh[i]);

    grid.sync();

    // ---- ph2: block 0 scans bhist -> bstart/bcur ----
    if (b == 0) {
        const int v = (tid < NB) ? bhist[tid] : 0;
        aux[tid] = v;
        __syncthreads();
        for (int off = 1; off < 256; off <<= 1) {
            const int t = (tid >= off) ? aux[tid - off] : 0;
            __syncthreads();
            aux[tid] += t;
            __syncthreads();
        }
        const int excl = aux[tid] - v;
        if (tid < NB) { bcur[tid] = excl; bstart[tid] = excl; }
        if (tid == 0) row_start[N_NODES] = N_EDGES;
    }

    grid.sync();

    // ---- ph3: reserve runs (lh from ph1 still live) + scatter ----
    for (int i = tid; i < NB; i += 256) {
        aux[i]  = 0;                                            // lcnt
        aux2[i] = (lh[i] > 0) ? atomicAdd(&bcur[i], lh[i]) : 0; // gbase
    }
    __syncthreads();
    for (int k = tid; k < CHUNK; k += 256) {
        const int e = e0 + k;
        if (e < N_EDGES) {
            const int d  = dst[e];
            const int bb = d >> 8;
            const int r  = atomicAdd(&aux[bb], 1);
            ebuf[aux2[bb] + r] = ((unsigned)d << 16) | (unsigned)src[e];
        }
    }

    grid.sync();

    // ---- ph4: counting sort of bucket b ----
    const int n0 = b << 8;
    const int R0 = bstart[b];
    const int R1 = (b + 1 < NB) ? bstart[b + 1] : N_EDGES;
    lh[tid] = 0; aux2[tid] = 0;
    __syncthreads();
    for (int i = R0 + tid; i < R1; i += 256)
        atomicAdd(&lh[(ebuf[i] >> 16) & 255], 1);
    __syncthreads();
    const int v4 = lh[tid];
    aux[tid] = v4;
    __syncthreads();
    for (int off = 1; off < 256; off <<= 1) {
        const int t = (tid >= off) ? aux[tid - off] : 0;
        __syncthreads();
        aux[tid] += t;
        __syncthreads();
    }
    const int excl4 = aux[tid] - v4;
    lh[tid] = excl4;                          // per-dst base lookup
    if (n0 + tid < N_NODES) row_start[n0 + tid] = R0 + excl4;
    __syncthreads();
    for (int i = R0 + tid; i < R1; i += 256) {
        const unsigned p = ebuf[i];
        const int dl = (p >> 16) & 255;
        const int r  = atomicAdd(&aux2[dl], 1);
        ssrc[R0 + lh[dl] + r] = (unsigned short)(p & 0xFFFFu);
    }
}

// ---------------------------------------------------------------------------
// K1: MFMA GEMM: feat[N,128](f32) x B[128,256](bf16) -> h_bf, idn_bf (bf16)
// + fused el/er epilogue. feat staged to LDS as bf16, XOR swizzle.
// ---------------------------------------------------------------------------
__global__ __launch_bounds__(256) void gemm_mfma(
    const float* __restrict__ feat,
    const unsigned short* __restrict__ Bp,
    const float* __restrict__ attn_l,
    const float* __restrict__ attn_r,
    unsigned short* __restrict__ h_bf,
    unsigned short* __restrict__ idn_bf,
    float* __restrict__ el,
    float* __restrict__ er)
{
    __shared__ __align__(16) unsigned short As[64 * IN_FEATS];   // 16 KiB
    const int tid  = threadIdx.x;
    const int row0 = blockIdx.x * 64;

    #pragma unroll
    for (int it = 0; it < 4; ++it) {
        const int chunk = it * 256 + tid;
        const int r  = chunk >> 4;
        const int c8 = (chunk & 15) * 8;
        float4 a = make_float4(0.f, 0.f, 0.f, 0.f);
        float4 b = make_float4(0.f, 0.f, 0.f, 0.f);
        if (row0 + r < N_NODES) {
            a = *(const float4*)&feat[(size_t)(row0 + r) * IN_FEATS + c8];
            b = *(const float4*)&feat[(size_t)(row0 + r) * IN_FEATS + c8 + 4];
        }
        uint4 p;
        p.x = (unsigned)f2bf(a.x) | ((unsigned)f2bf(a.y) << 16);
        p.y = (unsigned)f2bf(a.z) | ((unsigned)f2bf(a.w) << 16);
        p.z = (unsigned)f2bf(b.x) | ((unsigned)f2bf(b.y) << 16);
        p.w = (unsigned)f2bf(b.z) | ((unsigned)f2bf(b.w) << 16);
        const int byte = r * 256 + ((c8 * 2) ^ ((r & 7) << 4));
        *(uint4*)((char*)As + byte) = p;
    }
    __syncthreads();

    const int l    = tid & 63;
    const int w    = tid >> 6;
    const int colq = l & 15;
    const int kg   = l >> 4;

    f32x4 acc[4][4];
    #pragma unroll
    for (int m = 0; m < 4; ++m)
        #pragma unroll
        for (int n = 0; n < 4; ++n)
            acc[m][n] = (f32x4){0.f, 0.f, 0.f, 0.f};

    #pragma unroll
    for (int ks = 0; ks < 4; ++ks) {
        bf16x8 af[4], bfr[4];
        #pragma unroll
        for (int m = 0; m < 4; ++m) {
            const int row  = m * 16 + colq;
            const int byte = row * 256 + ((ks * 64 + kg * 16) ^ ((row & 7) << 4));
            af[m] = *(const bf16x8*)((const char*)As + byte);
        }
        #pragma unroll
        for (int n = 0; n < 4; ++n) {
            const int ng = w * 4 + n;
            bfr[n] = *(const bf16x8*)&Bp[(size_t)(((ng * 4 + ks) * 64) + l) * 8];
        }
        #pragma unroll
        for (int m = 0; m < 4; ++m)
            #pragma unroll
            for (int n = 0; n < 4; ++n)
                acc[m][n] = __builtin_amdgcn_mfma_f32_16x16x32_bf16(
                    af[m], bfr[n], acc[m][n], 0, 0, 0);
    }

    // h/idn stores: C[row][col], col = w*64 + n*16 + colq, row = m*16 + kg*4 + r
    #pragma unroll
    for (int m = 0; m < 4; ++m) {
        #pragma unroll
        for (int n = 0; n < 4; ++n) {
            const int col = w * 64 + n * 16 + colq;
            #pragma unroll
            for (int r = 0; r < 4; ++r) {
                const int row = row0 + m * 16 + kg * 4 + r;
                if (row < N_NODES) {
                    const unsigned short hv = f2bf(acc[m][n][r]);
                    if (col < HF) h_bf[(size_t)row * HF + col] = hv;
                    else          idn_bf[(size_t)row * HF + (col - HF)] = hv;
                }
            }
        }
    }

    // el/er epilogue: waves 0,1 hold h columns. head = w*2 + (n>>1).
    if (w < 2) {
        float al_n[4], ar_n[4];
        #pragma unroll
        for (int n = 0; n < 4; ++n) {
            al_n[n] = attn_l[w * 64 + n * 16 + colq];
            ar_n[n] = attn_r[w * 64 + n * 16 + colq];
        }
        #pragma unroll
        for (int m = 0; m < 4; ++m) {
            #pragma unroll
            for (int r = 0; r < 4; ++r) {
                float pl01 = acc[m][0][r] * al_n[0] + acc[m][1][r] * al_n[1];
                float pl23 = acc[m][2][r] * al_n[2] + acc[m][3][r] * al_n[3];
                float pr01 = acc[m][0][r] * ar_n[0] + acc[m][1][r] * ar_n[1];
                float pr23 = acc[m][2][r] * ar_n[2] + acc[m][3][r] * ar_n[3];
                #pragma unroll
                for (int off = 1; off < 16; off <<= 1) {
                    pl01 += __shfl_xor(pl01, off);
                    pl23 += __shfl_xor(pl23, off);
                    pr01 += __shfl_xor(pr01, off);
                    pr23 += __shfl_xor(pr23, off);
                }
                const int row = row0 + m * 16 + kg * 4 + r;
                if (colq == 0 && row < N_NODES) {
                    el[row * 4 + w * 2 + 0] = pl01;
                    el[row * 4 + w * 2 + 1] = pl23;
                    er[row * 4 + w * 2 + 0] = pr01;
                    er[row * 4 + w * 2 + 1] = pr23;
                }
            }
        }
    }
}

// ---------------------------------------------------------------------------
// K2: fused per-destination kernel. One wave per dst node, 8 edges/iter.
// q=lane>>3 (edge slot 0..7), sub=lane&7 (features sub*16..+15, 2x uint4),
// head hh=sub>>1. No max pass (softmax shift-invariant; logits clamped at 25).
// ---------------------------------------------------------------------------
__global__ __launch_bounds__(256) void msg_kernel(
    const unsigned short* __restrict__ h_bf,
    const unsigned short* __restrict__ idn_bf,
    const float* __restrict__ el,
    const float* __restrict__ er,
    const int* __restrict__ row_start,
    const unsigned short* __restrict__ ssrc,
    const float* __restrict__ se_w1,   // [4]
    const float* __restrict__ se_w2,   // [4]
    float* __restrict__ out)
{
    const int wid  = (blockIdx.x * 256 + threadIdx.x) >> 6;
    const int lane = threadIdx.x & 63;
    if (wid >= N_NODES) return;
    const int n   = wid;
    const int q   = lane >> 3;
    const int sub = lane & 7;
    const int hh  = sub >> 1;
    const int f0  = sub * 16;

    const float erh = er[n * 4 + hh];
    const int s0 = row_start[n], s1 = row_start[n + 1];

    float a[16];
    #pragma unroll
    for (int j = 0; j < 16; ++j) a[j] = 0.f;
    float dsum = 0.f;

    for (int i = s0; i < s1; i += 8) {
        const int e   = i + q;
        const bool ok = e < s1;
        const int s   = ssrc[ok ? e : s0];
        float ev = el[s * 4 + hh] + erh;
        ev = ev > 0.f ? ev : NEG_SLOPE * ev;
        ev = fminf(ev, 25.f);
        const float ex = ok ? __expf(ev) : 0.f;
        dsum += ex;
        const uint4 hv0 = *(const uint4*)&h_bf[(size_t)s * HF + f0];
        const uint4 hv1 = *(const uint4*)&h_bf[(size_t)s * HF + f0 + 8];
        float lo, hi;
        bf2x2(hv0.x, lo, hi); a[0]  = fmaf(ex, lo, a[0]);  a[1]  = fmaf(ex, hi, a[1]);
        bf2x2(hv0.y, lo, hi); a[2]  = fmaf(ex, lo, a[2]);  a[3]  = fmaf(ex, hi, a[3]);
        bf2x2(hv0.z, lo, hi); a[4]  = fmaf(ex, lo, a[4]);  a[5]  = fmaf(ex, hi, a[5]);
        bf2x2(hv0.w, lo, hi); a[6]  = fmaf(ex, lo, a[6]);  a[7]  = fmaf(ex, hi, a[7]);
        bf2x2(hv1.x, lo, hi); a[8]  = fmaf(ex, lo, a[8]);  a[9]  = fmaf(ex, hi, a[9]);
        bf2x2(hv1.y, lo, hi); a[10] = fmaf(ex, lo, a[10]); a[11] = fmaf(ex, hi, a[11]);
        bf2x2(hv1.z, lo, hi); a[12] = fmaf(ex, lo, a[12]); a[13] = fmaf(ex, hi, a[13]);
        bf2x2(hv1.w, lo, hi); a[14] = fmaf(ex, lo, a[14]); a[15] = fmaf(ex, hi, a[15]);
    }

    // reduce across the 8 edge slots (lane bits 5,4,3)
    dsum += __shfl_xor(dsum, 32);
    dsum += __shfl_xor(dsum, 16);
    dsum += __shfl_xor(dsum, 8);
    #pragma unroll
    for (int j = 0; j < 16; ++j) {
        a[j] += __shfl_xor(a[j], 32);
        a[j] += __shfl_xor(a[j], 16);
        a[j] += __shfl_xor(a[j], 8);
    }

    const float inv = (s1 > s0) ? 1.f / dsum : 0.f;
    #pragma unroll
    for (int j = 0; j < 16; ++j) a[j] *= inv;

    // SE gate: head hh spans lanes {2*hh, 2*hh+1} (16 feats each)
    float part = 0.f;
    #pragma unroll
    for (int j = 0; j < 16; ++j) part += a[j];
    part += __shfl_xor(part, 1);
    const float y  = part * (1.f / 32.f);
    const float y0 = __shfl(y, 0), y1 = __shfl(y, 2);
    const float y2 = __shfl(y, 4), y3 = __shfl(y, 6);
    float z = y0 * se_w1[0] + y1 * se_w1[1] + y2 * se_w1[2] + y3 * se_w1[3];
    z = fmaxf(z, 0.f);
    const float gate = 1.f / (1.f + __expf(-z * se_w2[hh]));

    if (q == 0) {
        const uint4 iv0 = *(const uint4*)&idn_bf[(size_t)n * HF + f0];
        const uint4 iv1 = *(const uint4*)&idn_bf[(size_t)n * HF + f0 + 8];
        float o[16], lo, hi;
        bf2x2(iv0.x, lo, hi); o[0]  = fmaf(a[0],  gate, lo); o[1]  = fmaf(a[1],  gate, hi);
        bf2x2(iv0.y, lo, hi); o[2]  = fmaf(a[2],  gate, lo); o[3]  = fmaf(a[3],  gate, hi);
        bf2x2(iv0.z, lo, hi); o[4]  = fmaf(a[4],  gate, lo); o[5]  = fmaf(a[5],  gate, hi);
        bf2x2(iv0.w, lo, hi); o[6]  = fmaf(a[6],  gate, lo); o[7]  = fmaf(a[7],  gate, hi);
        bf2x2(iv1.x, lo, hi); o[8]  = fmaf(a[8],  gate, lo); o[9]  = fmaf(a[9],  gate, hi);
        bf2x2(iv1.y, lo, hi); o[10] = fmaf(a[10], gate, lo); o[11] = fmaf(a[11], gate, hi);
        bf2x2(iv1.z, lo, hi); o[12] = fmaf(a[12], gate, lo); o[13] = fmaf(a[13], gate, hi);
        bf2x2(iv1.w, lo, hi); o[14] = fmaf(a[14], gate, lo); o[15] = fmaf(a[15], gate, hi);
        float* op = &out[(size_t)n * HF + f0];
        *(float4*)&op[0]  = make_float4(o[0],  o[1],  o[2],  o[3]);
        *(float4*)&op[4]  = make_float4(o[4],  o[5],  o[6],  o[7]);
        *(float4*)&op[8]  = make_float4(o[8],  o[9],  o[10], o[11]);
        *(float4*)&op[12] = make_float4(o[12], o[13], o[14], o[15]);
    }
}

// ---------------------------------------------------------------------------
extern "C" void kernel_launch(void* const* d_in, const int* in_sizes, int n_in,
                              void* d_out, int out_size, void* d_ws, size_t ws_size,
                              hipStream_t stream)
{
    const float* feat   = (const float*)d_in[0];
    const float* Wfc    = (const float*)d_in[1];
    const float* attn_l = (const float*)d_in[2];
    const float* attn_r = (const float*)d_in[3];
    const float* se_w1  = (const float*)d_in[4];
    const float* se_w2  = (const float*)d_in[5];
    const float* Widn   = (const float*)d_in[6];
    const int*   src    = (const int*)d_in[7];
    const int*   dst    = (const int*)d_in[8];
    float* out = (float*)d_out;

    char* ws = (char*)d_ws;
    size_t off = 0;
    auto alloc = [&](size_t bytes) -> void* {
        void* p = ws + off;
        off = (off + bytes + 255) & ~(size_t)255;
        return p;
    };
    unsigned short* h_bf   = (unsigned short*)alloc((size_t)N_NODES * HF * 2);
    unsigned short* idn_bf = (unsigned short*)alloc((size_t)N_NODES * HF * 2);
    unsigned short* Bp     = (unsigned short*)alloc((size_t)IN_FEATS * 256 * 2);
    float* el         = (float*)alloc((size_t)N_NODES * 4 * 4);
    float* er         = (float*)alloc((size_t)N_NODES * 4 * 4);
    int*   bhist      = (int*)alloc((size_t)NB * 4);
    int*   bcur       = (int*)alloc((size_t)NB * 4);
    int*   bstart     = (int*)alloc((size_t)NB * 4);
    int*   row_start  = (int*)alloc((size_t)(N_NODES + 1) * 4);
    unsigned* ebuf    = (unsigned*)alloc((size_t)N_EDGES * 4);
    unsigned short* ssrc = (unsigned short*)alloc((size_t)N_EDGES * 2);

    hipMemsetAsync(bhist, 0, (size_t)NB * 4, stream);

    // cooperative CSR build (pack + hist + scan + bin + sort in one dispatch)
    {
        const float* a0 = Wfc;  const float* a1 = Widn;
        unsigned short* a2 = Bp;
        const int* a3 = src;    const int* a4 = dst;
        int* a5 = bhist; int* a6 = bcur; int* a7 = bstart; int* a8 = row_start;
        unsigned* a9 = ebuf; unsigned short* a10 = ssrc;
        void* args[] = {&a0, &a1, &a2, &a3, &a4, &a5, &a6, &a7, &a8, &a9, &a10};
        hipLaunchCooperativeKernel((void*)build_csr, dim3(NB), dim3(256),
                                   args, 0, stream);
    }

    gemm_mfma<<<(N_NODES + 63) / 64, 256, 0, stream>>>(feat, Bp, attn_l, attn_r,
                                                       h_bf, idn_bf, el, er);
    msg_kernel<<<(N_NODES * 64) / 256, 256, 0, stream>>>(h_bf, idn_bf, el, er, row_start,
                                                         ssrc, se_w1, se_w2, out);
}